// Round 7
// baseline (763.923 us; speedup 1.0000x reference)
//
#include <hip/hip_runtime.h>
#include <hip/hip_bf16.h>

typedef __attribute__((ext_vector_type(8))) short s8v;
typedef __attribute__((ext_vector_type(4))) short s4v;
typedef __attribute__((ext_vector_type(4))) float f4v;
typedef __attribute__((ext_vector_type(4))) __fp16 h4v;
typedef __attribute__((ext_vector_type(2))) __fp16 h2v;

#define MFMA32(A,B,C) __builtin_amdgcn_mfma_f32_16x16x32_bf16(A,B,C,0,0,0)
#define MFMA16(A,B,C) __builtin_amdgcn_mfma_f32_16x16x16bf16_1k(A,B,C,0,0,0)

__device__ __forceinline__ unsigned short f2bf(float f){
  unsigned int u = __float_as_uint(f);
  u += 0x7FFFu + ((u>>16)&1u);
  return (unsigned short)(u>>16);
}
__device__ __forceinline__ float bf2f(unsigned short s){
  return __uint_as_float(((unsigned int)s)<<16);
}

// packed f32x4 -> bf16x4 (v_cvt_pk_bf16_f32 on gfx950)
__device__ __forceinline__ s4v pack4(float x, float y, float z, float w){
  s4v r;
#if __has_builtin(__builtin_amdgcn_cvt_pk_bf16_f32)
  typedef __attribute__((ext_vector_type(2))) __bf16 b2;
  b2 lo = __builtin_amdgcn_cvt_pk_bf16_f32(x,y);
  b2 hi = __builtin_amdgcn_cvt_pk_bf16_f32(z,w);
  int2 p;
  __builtin_memcpy(&p.x,&lo,4);
  __builtin_memcpy(&p.y,&hi,4);
  __builtin_memcpy(&r,&p,8);
#else
  r[0]=(short)f2bf(x); r[1]=(short)f2bf(y); r[2]=(short)f2bf(z); r[3]=(short)f2bf(w);
#endif
  return r;
}

// packed f32x4 -> fp16x4 (v_cvt_pkrtz_f16_f32)
__device__ __forceinline__ h4v packh4(float x, float y, float z, float w){
  h2v lo = __builtin_amdgcn_cvt_pkrtz(x,y);
  h2v hi = __builtin_amdgcn_cvt_pkrtz(z,w);
  h4v r;
  __builtin_memcpy(&r, &lo, 4);
  __builtin_memcpy(((char*)&r)+4, &hi, 4);
  return r;
}

// log2(e)/8  (fold the 1/sqrt(dh)=1/8 score scale into exp2)
#define EXPC 0.18033688011112042f

// ---------------------------------------------------------------------------
// K0: Wo' [o][h*64+j] = Wo[o][j*16+h], bf16
// ---------------------------------------------------------------------------
__global__ void pack_wo(const float* __restrict__ wo, unsigned short* __restrict__ wop){
  int idx = blockIdx.x*256 + threadIdx.x;
  if(idx >= 1024*1024) return;
  int o = idx >> 10, r = idx & 1023, h = r >> 6, j = r & 63;
  wop[idx] = f2bf(wo[o*1024 + j*16 + h]);
}

// ---------------------------------------------------------------------------
// K1: projections. C[m,n] = sum_k A[m,k] * W[n,k] + bias[n]
//   z=0: KEY  -> kh[b][h][s][j]   z=1: QUERY-> qh   z=2: VALUE-> vt[b][h][j][s]
// ---------------------------------------------------------------------------
__global__ __launch_bounds__(256) void proj_gemm(
    const float* __restrict__ KEY, const float* __restrict__ VALUE, const float* __restrict__ QUERY,
    const float* __restrict__ Wk, const float* __restrict__ bk,
    const float* __restrict__ Wq, const float* __restrict__ bq,
    const float* __restrict__ Wv, const float* __restrict__ bv,
    unsigned short* __restrict__ kh, unsigned short* __restrict__ qh,
    unsigned short* __restrict__ vt)
{
  __shared__ short As[128*64];
  __shared__ short Bs[128*64];
  const int t = threadIdx.x;
  const int z = blockIdx.z;
  const float* A; const float* W; const float* bias;
  if(z==0){A=KEY;   W=Wk; bias=bk;}
  else if(z==1){A=QUERY; W=Wq; bias=bq;}
  else {A=VALUE; W=Wv; bias=bv;}
  const int m0 = blockIdx.x*128, n0 = blockIdx.y*128;
  const int l = t&63, w = t>>6;
  const int wm = (w>>1)*64, wn = (w&1)*64;
  const int row16 = l&15, quad = l>>4;
  f4v acc[4][4];
  #pragma unroll
  for(int i=0;i<4;i++)
    #pragma unroll
    for(int j=0;j<4;j++) acc[i][j] = (f4v){0.f,0.f,0.f,0.f};

  const int sr = t>>4, sc = t&15;
  for(int k0=0;k0<1024;k0+=64){
    #pragma unroll
    for(int p=0;p<8;p++){
      float4 av = *(const float4*)&A[(size_t)(m0 + p*16 + sr)*1024 + k0 + sc*4];
      float4 bvv= *(const float4*)&W[(size_t)(n0 + p*16 + sr)*1024 + k0 + sc*4];
      *(s4v*)&As[(p*16+sr)*64 + sc*4] = pack4(av.x,av.y,av.z,av.w);
      *(s4v*)&Bs[(p*16+sr)*64 + sc*4] = pack4(bvv.x,bvv.y,bvv.z,bvv.w);
    }
    __syncthreads();
    #pragma unroll
    for(int kk=0; kk<64; kk+=32){
      s8v af[4], bf[4];
      #pragma unroll
      for(int mt=0;mt<4;mt++) af[mt] = *(const s8v*)&As[(wm+mt*16+row16)*64 + kk + quad*8];
      #pragma unroll
      for(int nt=0;nt<4;nt++) bf[nt] = *(const s8v*)&Bs[(wn+nt*16+row16)*64 + kk + quad*8];
      #pragma unroll
      for(int mt=0;mt<4;mt++)
        #pragma unroll
        for(int nt=0;nt<4;nt++)
          acc[mt][nt] = MFMA32(af[mt], bf[nt], acc[mt][nt]);
    }
    __syncthreads();
  }

  #pragma unroll
  for(int nt=0;nt<4;nt++){
    const int n = n0 + wn + nt*16 + row16;
    const float bias_n = bias[n];
    const int hh = n & 15;
    const int jj2 = n >> 4;
    #pragma unroll
    for(int mt=0;mt<4;mt++){
      #pragma unroll
      for(int r=0;r<4;r++){
        const int m = m0 + wm + mt*16 + quad*4 + r;
        const float val = acc[mt][nt][r] + bias_n;
        const int bb = m>>11, ss = m&2047;
        if(z==2)
          vt[(size_t)((bb*16+hh)*64 + jj2)*2048 + ss] = f2bf(val);
        else if(z==0)
          kh[(size_t)((bb*16+hh)*2048 + ss)*64 + jj2] = f2bf(val);
        else
          qh[(size_t)((bb*16+hh)*2048 + ss)*64 + jj2] = f2bf(val);
      }
    }
  }
}

// ---------------------------------------------------------------------------
// K2a: head-softmax denominators, fully lane-local (NO LDS, NO barriers).
// Wave owns (i64-slice, q16); loops all 16 heads; MFMA C-layout position of
// score (i,q) is identical for every head, so the 16-way sum is per-lane.
// Writes rden = 1/sum as fp16 in [b][q][i] layout -> each lane's 4
// consecutive-i values are ONE contiguous 8-B store (and an 8-B load in pv).
// ---------------------------------------------------------------------------
__global__ __launch_bounds__(256) void denom_pass(
    const unsigned short* __restrict__ kh, const unsigned short* __restrict__ qh,
    unsigned short* __restrict__ rden)
{
  const int t=threadIdx.x, l=t&63, w=t>>6;
  const int row16=l&15, quad=l>>4;
  const int i0 = blockIdx.x*64;
  const int q0 = blockIdx.y*64 + w*16;
  const int b  = blockIdx.z;
  f4v dsum[4];
  #pragma unroll
  for(int s=0;s<4;s++) dsum[s] = (f4v){0.f,0.f,0.f,0.f};
  const unsigned short* kbase = &kh[(size_t)((b*16)*2048 + i0 + row16)*64];
  const unsigned short* qbase = &qh[(size_t)((b*16)*2048 + q0 + row16)*64];
  for(int h=0;h<16;h++){
    const unsigned short* qp = qbase + (size_t)h*131072;
    const unsigned short* kp = kbase + (size_t)h*131072;
    s8v qf0 = *(const s8v*)&qp[quad*8];
    s8v qf1 = *(const s8v*)&qp[32+quad*8];
    #pragma unroll
    for(int sub=0;sub<4;sub++){
      f4v S = (f4v){0.f,0.f,0.f,0.f};
      S = MFMA32(*(const s8v*)&kp[sub*1024+quad*8],    qf0, S);
      S = MFMA32(*(const s8v*)&kp[sub*1024+32+quad*8], qf1, S);
      #pragma unroll
      for(int r=0;r<4;r++)
        dsum[sub][r] += __builtin_amdgcn_exp2f(S[r]*EXPC);
    }
  }
  unsigned short* rp = &rden[((size_t)(b*2048 + q0 + row16))*2048 + i0 + quad*4];
  #pragma unroll
  for(int sub=0;sub<4;sub++){
    h4v hv = packh4(__builtin_amdgcn_rcpf(dsum[sub][0]),
                    __builtin_amdgcn_rcpf(dsum[sub][1]),
                    __builtin_amdgcn_rcpf(dsum[sub][2]),
                    __builtin_amdgcn_rcpf(dsum[sub][3]));
    *(h4v*)&rp[sub*16] = hv;
  }
}

// ---------------------------------------------------------------------------
// K2b: PV pass — NO LDS, NO barriers. Wave = (q16, 2 heads); i-chunk 1024
// processed as two sequential 512-windows so each XCD's L2 holds a 4 MB K/V
// window (comb=flat&3 pins (b,ihh) to XCD pairs). P = exp * rden(b64 load),
// stays in registers (MFMA C-layout == MFMA16 B-fragment layout).
// ---------------------------------------------------------------------------
__global__ __launch_bounds__(256) void pv_pass(
    const unsigned short* __restrict__ kh, const unsigned short* __restrict__ qh,
    const unsigned short* __restrict__ vt, const unsigned short* __restrict__ rden,
    unsigned short* __restrict__ opart)
{
  const int t=threadIdx.x, l=t&63, w=t>>6;
  const int row16=l&15, quad=l>>4;
  const int flat = blockIdx.x;
  const int comb = flat & 3;           // == ihh*2 + b
  const int qb   = (flat>>2) & 127;
  const int hq   = flat >> 9;          // 0..1
  const int b    = comb & 1;
  const int ihh  = comb >> 1;          // 0..1 (i-chunk of 1024)
  const int q0 = qb*16;
  const int h0 = hq*8 + w*2;

  const unsigned short* qp0 = &qh[(size_t)((b*16+h0)*2048 + q0 + row16)*64];
  const unsigned short* kb0 = &kh[(size_t)((b*16+h0)*2048 + row16)*64];
  const unsigned short* vb0 = &vt[(size_t)((b*16+h0)*64 + row16)*2048];
  const unsigned short* rb  = &rden[(size_t)(b*2048 + q0 + row16)*2048 + quad*4];

  s8v qf[2][2];
  #pragma unroll
  for(int hh=0;hh<2;hh++){
    const unsigned short* qp = qp0 + (size_t)hh*131072;
    qf[hh][0] = *(const s8v*)&qp[quad*8];
    qf[hh][1] = *(const s8v*)&qp[32+quad*8];
  }
  f4v o[2][4];
  #pragma unroll
  for(int i=0;i<2;i++)
    #pragma unroll
    for(int j=0;j<4;j++) o[i][j] = (f4v){0.f,0.f,0.f,0.f};

  for(int ic=0; ic<2; ic++){
    const int ibase = ihh*1024 + ic*512;
    for(int ii=0; ii<512; ii+=32){
      const int i0 = ibase + ii;
      h4v rd0 = *(const h4v*)&rb[i0];
      h4v rd1 = *(const h4v*)&rb[i0+16];
      #pragma unroll
      for(int hh=0;hh<2;hh++){
        const unsigned short* kp = kb0 + (size_t)hh*131072 + (size_t)i0*64;
        f4v S0 = (f4v){0.f,0.f,0.f,0.f};
        f4v S1 = (f4v){0.f,0.f,0.f,0.f};
        S0 = MFMA32(*(const s8v*)&kp[quad*8],         qf[hh][0], S0);
        S0 = MFMA32(*(const s8v*)&kp[32+quad*8],      qf[hh][1], S0);
        S1 = MFMA32(*(const s8v*)&kp[1024+quad*8],    qf[hh][0], S1);
        S1 = MFMA32(*(const s8v*)&kp[1024+32+quad*8], qf[hh][1], S1);
        s4v p0 = pack4(__builtin_amdgcn_exp2f(S0[0]*EXPC)*(float)rd0[0],
                       __builtin_amdgcn_exp2f(S0[1]*EXPC)*(float)rd0[1],
                       __builtin_amdgcn_exp2f(S0[2]*EXPC)*(float)rd0[2],
                       __builtin_amdgcn_exp2f(S0[3]*EXPC)*(float)rd0[3]);
        s4v p1 = pack4(__builtin_amdgcn_exp2f(S1[0]*EXPC)*(float)rd1[0],
                       __builtin_amdgcn_exp2f(S1[1]*EXPC)*(float)rd1[1],
                       __builtin_amdgcn_exp2f(S1[2]*EXPC)*(float)rd1[2],
                       __builtin_amdgcn_exp2f(S1[3]*EXPC)*(float)rd1[3]);
        const unsigned short* vbh = vb0 + (size_t)hh*131072 + i0;
        #pragma unroll
        for(int jt=0;jt<4;jt++){
          const unsigned short* vp = vbh + (size_t)jt*16*2048;
          s4v v0 = *(const s4v*)&vp[quad*4];
          s4v v1 = *(const s4v*)&vp[16+quad*4];
          o[hh][jt] = MFMA16(v0, p0, o[hh][jt]);
          o[hh][jt] = MFMA16(v1, p1, o[hh][jt]);
        }
      }
    }
  }
  // opart[ihh][b*2048+q][1024], ihh-stride 4194304 elems
  unsigned short* ob = &opart[(size_t)ihh*4194304 + ((size_t)(b*2048 + q0+row16))*1024 + h0*64 + quad*4];
  #pragma unroll
  for(int hh=0;hh<2;hh++){
    #pragma unroll
    for(int jt=0;jt<4;jt++)
      *(s4v*)&ob[hh*64 + jt*16] = pack4(o[hh][jt][0],o[hh][jt][1],o[hh][jt][2],o[hh][jt][3]);
  }
}

// ---------------------------------------------------------------------------
// K3: reduce the 2 i-chunk partials -> out2 bf16
// ---------------------------------------------------------------------------
__global__ __launch_bounds__(256) void reduce_o(
    const unsigned short* __restrict__ op, unsigned short* __restrict__ out2)
{
  size_t e = ((size_t)blockIdx.x*256 + threadIdx.x)*8;
  float s[8];
  #pragma unroll
  for(int i=0;i<8;i++) s[i]=0.f;
  #pragma unroll
  for(int p=0;p<2;p++){
    s8v a = *(const s8v*)&op[(size_t)p*4194304 + e];
    #pragma unroll
    for(int i=0;i<8;i++) s[i] += bf2f((unsigned short)a[i]);
  }
  s4v lo = pack4(s[0],s[1],s[2],s[3]);
  s4v hi = pack4(s[4],s[5],s[6],s[7]);
  s8v r;
  #pragma unroll
  for(int i=0;i<4;i++){ r[i] = lo[i]; r[i+4] = hi[i]; }
  *(s8v*)&out2[e] = r;
}

// ---------------------------------------------------------------------------
// K4: res[m][n] = sum_k out2[m,k]*WoP[n,k] + bo[n], fp32 out
// ---------------------------------------------------------------------------
__global__ __launch_bounds__(256) void out_gemm(
    const unsigned short* __restrict__ A, const unsigned short* __restrict__ Bm,
    const float* __restrict__ bias, float* __restrict__ out)
{
  __shared__ short As[128*64];
  __shared__ short Bs[128*64];
  const int t=threadIdx.x, l=t&63, w=t>>6;
  const int row16=l&15, quad=l>>4;
  const int m0=blockIdx.x*128, n0=blockIdx.y*128;
  const int wm=(w>>1)*64, wn=(w&1)*64;
  f4v acc[4][4];
  #pragma unroll
  for(int i=0;i<4;i++)
    #pragma unroll
    for(int j=0;j<4;j++) acc[i][j] = (f4v){0.f,0.f,0.f,0.f};

  const int sr=t>>3, sc=(t&7)*8;
  for(int k0=0;k0<1024;k0+=64){
    #pragma unroll
    for(int p=0;p<4;p++){
      *(s8v*)&As[(p*32+sr)*64 + sc] = *(const s8v*)&A [(size_t)(m0+p*32+sr)*1024 + k0 + sc];
      *(s8v*)&Bs[(p*32+sr)*64 + sc] = *(const s8v*)&Bm[(size_t)(n0+p*32+sr)*1024 + k0 + sc];
    }
    __syncthreads();
    #pragma unroll
    for(int kk=0; kk<64; kk+=32){
      s8v af[4], bf[4];
      #pragma unroll
      for(int mt=0;mt<4;mt++) af[mt] = *(const s8v*)&As[(wm+mt*16+row16)*64 + kk + quad*8];
      #pragma unroll
      for(int nt=0;nt<4;nt++) bf[nt] = *(const s8v*)&Bs[(wn+nt*16+row16)*64 + kk + quad*8];
      #pragma unroll
      for(int mt=0;mt<4;mt++)
        #pragma unroll
        for(int nt=0;nt<4;nt++)
          acc[mt][nt] = MFMA32(af[mt], bf[nt], acc[mt][nt]);
    }
    __syncthreads();
  }
  #pragma unroll
  for(int nt=0;nt<4;nt++){
    const int n = n0+wn+nt*16+row16;
    const float bias_n = bias[n];
    #pragma unroll
    for(int mt=0;mt<4;mt++)
      #pragma unroll
      for(int r=0;r<4;r++){
        const int m = m0+wm+mt*16+quad*4+r;
        out[(size_t)m*1024 + n] = acc[mt][nt][r] + bias_n;
      }
  }
}

// ---------------------------------------------------------------------------
extern "C" void kernel_launch(void* const* d_in, const int* in_sizes, int n_in,
                              void* d_out, int out_size, void* d_ws, size_t ws_size,
                              hipStream_t stream)
{
  const float* KEY   = (const float*)d_in[0];
  const float* VALUE = (const float*)d_in[1];
  const float* QUERY = (const float*)d_in[2];
  const float* Wk = (const float*)d_in[3];
  const float* bk = (const float*)d_in[4];
  const float* Wq = (const float*)d_in[5];
  const float* bq = (const float*)d_in[6];
  const float* Wv = (const float*)d_in[7];
  const float* bv = (const float*)d_in[8];
  const float* Wo = (const float*)d_in[9];
  const float* bo = (const float*)d_in[10];

  char* ws = (char*)d_ws;
  unsigned short* kh   = (unsigned short*)(ws);                 //  8 MiB [2][16][2048][64]
  unsigned short* qh   = (unsigned short*)(ws +  8388608);      //  8 MiB
  unsigned short* vt   = (unsigned short*)(ws + 16777216);      //  8 MiB [2][16][64][2048]
  unsigned short* wop  = (unsigned short*)(ws + 25165824);      //  2 MiB
  unsigned short* rden = (unsigned short*)(ws + 27262976);      // 16 MiB fp16 [2][2048][2048]
  unsigned short* opart= (unsigned short*)(ws + 44040192);      // 16 MiB [2ihh][4096][1024]
  unsigned short* out2 = (unsigned short*)(ws);                 //  aliases kh (dead by reduce_o)

  pack_wo   <<<dim3(4096),    dim3(256), 0, stream>>>(Wo, wop);
  proj_gemm <<<dim3(32,8,3),  dim3(256), 0, stream>>>(KEY,VALUE,QUERY,Wk,bk,Wq,bq,Wv,bv,kh,qh,vt);
  denom_pass<<<dim3(32,32,2), dim3(256), 0, stream>>>(kh,qh,rden);
  pv_pass   <<<dim3(1024),    dim3(256), 0, stream>>>(kh,qh,vt,rden,opart);
  reduce_o  <<<dim3(2048),    dim3(256), 0, stream>>>(opart,out2);
  out_gemm  <<<dim3(32,8),    dim3(256), 0, stream>>>(out2,wop,bo,(float*)d_out);
}